// Round 1
// baseline (226.528 us; speedup 1.0000x reference)
//
#include <hip/hip_runtime.h>
#include <hip/hip_bf16.h>

#define DIMC 1024
#define HEADS 16
#define HD 64
#define BATCH 2
#define SEQ 2048

typedef __bf16 bf16;
typedef __bf16 bf16x4 __attribute__((ext_vector_type(4)));
typedef __bf16 bf16x8 __attribute__((ext_vector_type(8)));
typedef float f32x4 __attribute__((ext_vector_type(4)));

__device__ inline f32x4 mfma_bf16(bf16x8 a, bf16x8 b, f32x4 c) {
    return __builtin_amdgcn_mfma_f32_16x16x32_bf16(a, b, c, 0, 0, 0);
}

// store 8 bf16 to LDS as two b64 (row strides are 8B- but not 16B-aligned)
__device__ inline void st8(bf16* p, bf16x8 v) {
    *(bf16x4*)p       = *(bf16x4*)&v;
    *(bf16x4*)(p + 4) = *((bf16x4*)&v + 1);
}
// load one MFMA operand fragment: elements 0..3 at k, 4..7 at k+16
__device__ inline bf16x8 ld_frag(const bf16* p) {
    bf16x8 r;
    *(bf16x4*)&r       = *(const bf16x4*)p;
    *((bf16x4*)&r + 1) = *(const bf16x4*)(p + 16);
    return r;
}

// ---------------- prep: sanitize+clip x -> bf16 ----------------
__global__ __launch_bounds__(256) void k_prep_x(const float* __restrict__ x,
                                                bf16* __restrict__ xb) {
    int i = blockIdx.x * 256 + threadIdx.x;
    float4 v = ((const float4*)x)[i];
    float a[4] = {v.x, v.y, v.z, v.w};
    bf16x4 o;
#pragma unroll
    for (int j = 0; j < 4; ++j) {
        float f = a[j];
        f = __builtin_isfinite(f) ? fminf(fmaxf(f, -10000.f), 10000.f) : 0.f;
        o[j] = (bf16)f;
    }
    ((bf16x4*)xb)[i] = o;
}

__global__ __launch_bounds__(256) void k_cast(const float* __restrict__ a,
                                              bf16* __restrict__ o) {
    int i = blockIdx.x * 256 + threadIdx.x;
    float4 v = ((const float4*)a)[i];
    bf16x4 r = {(bf16)v.x, (bf16)v.y, (bf16)v.z, (bf16)v.w};
    ((bf16x4*)o)[i] = r;
}

// ---------------- GEMM: C[M][N] = A[M][K] * Bt[N][K]^T ----------------
// 128x128 tile, 4 waves (2x2), each wave 64x64 = 4x4 frags of 16x16x32 MFMA.
template <bool OUT_BF16, bool BIAS, bool SANITIZE>
__global__ __launch_bounds__(256) void k_gemm_bt(const bf16* __restrict__ A,
                                                 const bf16* __restrict__ Bt,
                                                 void* __restrict__ Cv,
                                                 const float* __restrict__ bias,
                                                 int N, int K) {
    __shared__ bf16 As[128][68];
    __shared__ bf16 Bs[128][68];
    const int t = threadIdx.x;
    const int m0 = blockIdx.y * 128, n0 = blockIdx.x * 128;
    const int w = t >> 6, lane = t & 63;
    const int wm = (w >> 1) * 64, wn = (w & 1) * 64;
    const int lr = lane & 15, lg = lane >> 4;

    f32x4 acc[4][4];
#pragma unroll
    for (int i = 0; i < 4; ++i)
#pragma unroll
        for (int j = 0; j < 4; ++j) acc[i][j] = 0.0f;

    for (int k0 = 0; k0 < K; k0 += 64) {
#pragma unroll
        for (int i = 0; i < 4; ++i) {
            int c = t + i * 256;          // 0..1023
            int r = c >> 3, col = (c & 7) * 8;
            bf16x8 av = *(const bf16x8*)(A + (size_t)(m0 + r) * K + k0 + col);
            bf16x8 bv = *(const bf16x8*)(Bt + (size_t)(n0 + r) * K + k0 + col);
            st8(&As[r][col], av);
            st8(&Bs[r][col], bv);
        }
        __syncthreads();
#pragma unroll
        for (int kk = 0; kk < 2; ++kk) {
            bf16x8 af[4], bfr[4];
#pragma unroll
            for (int mi = 0; mi < 4; ++mi)
                af[mi] = ld_frag(&As[wm + mi * 16 + lr][kk * 32 + lg * 4]);
#pragma unroll
            for (int ni = 0; ni < 4; ++ni)
                bfr[ni] = ld_frag(&Bs[wn + ni * 16 + lr][kk * 32 + lg * 4]);
#pragma unroll
            for (int mi = 0; mi < 4; ++mi)
#pragma unroll
                for (int ni = 0; ni < 4; ++ni)
                    acc[mi][ni] = mfma_bf16(af[mi], bfr[ni], acc[mi][ni]);
        }
        __syncthreads();
    }
    // epilogue; C/D layout: col = lane&15, row = (lane>>4)*4 + reg
#pragma unroll
    for (int mi = 0; mi < 4; ++mi) {
#pragma unroll
        for (int ni = 0; ni < 4; ++ni) {
            int col = n0 + wn + ni * 16 + lr;
            float bval = BIAS ? bias[col] : 0.f;
#pragma unroll
            for (int r = 0; r < 4; ++r) {
                int row = m0 + wm + mi * 16 + lg * 4 + r;
                float v = acc[mi][ni][r];
                if (SANITIZE) v = __builtin_isfinite(v) ? v : 0.f;
                v += bval;
                if (OUT_BF16)
                    ((bf16*)Cv)[(size_t)row * N + col] = (bf16)v;
                else
                    ((float*)Cv)[(size_t)row * N + col] = v;
            }
        }
    }
}

// ---------------- postprocess: rmsnorm + rope, v transpose ----------------
// grid (32 lblocks, 16 heads, 2 batch) x 256 threads
__global__ __launch_bounds__(256) void k_post(const bf16* __restrict__ qkvb,
                                              const float* __restrict__ pe,
                                              const float* __restrict__ q_scale,
                                              const float* __restrict__ k_scale,
                                              bf16* __restrict__ qb,
                                              bf16* __restrict__ kb,
                                              bf16* __restrict__ vt) {
    const int lb = blockIdx.x, h = blockIdx.y, b = blockIdx.z;
    const int t = threadIdx.x;
    const int row = t >> 2, sub = t & 3;  // 64 rows x 4 lanes each
    const int l = lb * 64 + row;
    const int d0 = sub * 16;
    const size_t rowbase = ((size_t)(b * SEQ + l)) * (3 * DIMC) + h * HD;
    const size_t bh = (size_t)(b * HEADS + h);

#pragma unroll
    for (int qk = 0; qk < 2; ++qk) {
        const bf16* src = qkvb + rowbase + qk * DIMC + d0;
        const float* sc = qk ? k_scale : q_scale;
        bf16x8 v0 = *(const bf16x8*)src;
        bf16x8 v1 = *(const bf16x8*)(src + 8);
        float vals[16];
        float ss = 0.f;
#pragma unroll
        for (int j = 0; j < 8; ++j) {
            vals[j] = (float)v0[j];
            vals[8 + j] = (float)v1[j];
        }
#pragma unroll
        for (int j = 0; j < 16; ++j) ss += vals[j] * vals[j];
        ss += __shfl_xor(ss, 1, 64);
        ss += __shfl_xor(ss, 2, 64);
        float rms = rsqrtf(ss * (1.f / 64.f) + 1e-6f);
        // fold attention scale D^-0.5 and log2(e) into q
        const float outscale = qk ? 1.0f : 0.125f * 1.44269504088896340736f;
        bf16 ob[16];
#pragma unroll
        for (int j = 0; j < 16; j += 2) {
            int d = d0 + j;
            float e0 = vals[j] * rms * sc[d];
            float e1 = vals[j + 1] * rms * sc[d + 1];
            float4 pv = *(const float4*)(pe + (size_t)l * 128 + (d >> 1) * 4);
            float o0 = pv.x * e0 + pv.y * e1;
            float o1 = pv.z * e0 + pv.w * e1;
            ob[j] = (bf16)(o0 * outscale);
            ob[j + 1] = (bf16)(o1 * outscale);
        }
        bf16* dst = (qk ? kb : qb) + (bh * SEQ + l) * HD + d0;
        *(bf16x8*)dst = *(bf16x8*)&ob[0];
        *(bf16x8*)(dst + 8) = *(bf16x8*)&ob[8];
    }

    // V: cast + transpose to [B,H,D,L] via LDS
    __shared__ bf16 vlds[64][68];
    {
        const bf16* src = qkvb + rowbase + 2 * DIMC + d0;
        bf16x8 v0 = *(const bf16x8*)src;
        bf16x8 v1 = *(const bf16x8*)(src + 8);
        st8(&vlds[row][d0], v0);
        st8(&vlds[row][d0 + 8], v1);
    }
    __syncthreads();
    {
        const int d = t >> 2, c0 = (t & 3) * 16;
        bf16 ob[16];
#pragma unroll
        for (int j = 0; j < 16; ++j) ob[j] = vlds[c0 + j][d];
        bf16* dst = vt + (bh * HD + d) * SEQ + lb * 64 + c0;
        *(bf16x8*)dst = *(bf16x8*)&ob[0];
        *(bf16x8*)(dst + 8) = *(bf16x8*)&ob[8];
    }
}

// ---------------- flash attention ----------------
// grid (L/64 q-tiles, B*H), 256 threads = 4 waves, wave w -> q rows w*16..+16
__global__ __launch_bounds__(256) void k_attn(const bf16* __restrict__ Q,
                                              const bf16* __restrict__ Kb,
                                              const bf16* __restrict__ Vt,
                                              bf16* __restrict__ O) {
    __shared__ bf16 Qs[64][68];
    __shared__ bf16 Ks[64][68];
    __shared__ bf16 Vs[64][68];      // Vt tile: [d][key]
    __shared__ bf16 Ps[4][16][68];   // per-wave P
    const int qt = blockIdx.x, bh = blockIdx.y;
    const int b = bh >> 4, h = bh & 15;
    const int t = threadIdx.x, w = t >> 6, lane = t & 63;
    const int lr = lane & 15, lg = lane >> 4;
    const size_t baseQK = (size_t)bh * SEQ * HD;
    const size_t baseVt = (size_t)bh * HD * SEQ;

#pragma unroll
    for (int i = 0; i < 2; ++i) {
        int c = t + i * 256;
        int r = c >> 3, col = (c & 7) * 8;
        bf16x8 v = *(const bf16x8*)(Q + baseQK + (size_t)(qt * 64 + r) * HD + col);
        st8(&Qs[r][col], v);
    }
    __syncthreads();
    bf16x8 qf[2];
    qf[0] = ld_frag(&Qs[w * 16 + lr][lg * 4]);
    qf[1] = ld_frag(&Qs[w * 16 + lr][32 + lg * 4]);

    f32x4 oacc[4];
#pragma unroll
    for (int i = 0; i < 4; ++i) oacc[i] = 0.0f;
    float m_r[4], l_r[4];
#pragma unroll
    for (int r = 0; r < 4; ++r) {
        m_r[r] = -1e30f;
        l_r[r] = 0.f;
    }

    for (int kt = 0; kt < SEQ / 64; ++kt) {
        __syncthreads();  // all waves done reading Ks/Vs of prev tile
#pragma unroll
        for (int i = 0; i < 2; ++i) {
            int c = t + i * 256;
            int r = c >> 3, col = (c & 7) * 8;
            bf16x8 kv = *(const bf16x8*)(Kb + baseQK + (size_t)(kt * 64 + r) * HD + col);
            st8(&Ks[r][col], kv);
            bf16x8 vv = *(const bf16x8*)(Vt + baseVt + (size_t)r * SEQ + kt * 64 + col);
            st8(&Vs[r][col], vv);
        }
        __syncthreads();
        // scores: S[16 q][64 keys], q pre-scaled by D^-0.5*log2e
        f32x4 s[4];
#pragma unroll
        for (int nk = 0; nk < 4; ++nk) {
            f32x4 a = 0.0f;
            a = mfma_bf16(qf[0], ld_frag(&Ks[nk * 16 + lr][lg * 4]), a);
            a = mfma_bf16(qf[1], ld_frag(&Ks[nk * 16 + lr][32 + lg * 4]), a);
            s[nk] = a;
        }
        // online softmax (rows live on 16-lane groups; exp2 domain)
        float alpha[4];
#pragma unroll
        for (int r = 0; r < 4; ++r) {
            float tm = fmaxf(fmaxf(s[0][r], s[1][r]), fmaxf(s[2][r], s[3][r]));
            tm = fmaxf(tm, __shfl_xor(tm, 1, 64));
            tm = fmaxf(tm, __shfl_xor(tm, 2, 64));
            tm = fmaxf(tm, __shfl_xor(tm, 4, 64));
            tm = fmaxf(tm, __shfl_xor(tm, 8, 64));
            float mnew = fmaxf(m_r[r], tm);
            alpha[r] = exp2f(m_r[r] - mnew);
            m_r[r] = mnew;
            float rs = 0.f;
#pragma unroll
            for (int nk = 0; nk < 4; ++nk) {
                float p = exp2f(s[nk][r] - mnew);
                s[nk][r] = p;
                rs += p;
            }
            rs += __shfl_xor(rs, 1, 64);
            rs += __shfl_xor(rs, 2, 64);
            rs += __shfl_xor(rs, 4, 64);
            rs += __shfl_xor(rs, 8, 64);
            l_r[r] = l_r[r] * alpha[r] + rs;
        }
        // P -> wave-private LDS (same-wave DS ordering, no barrier needed)
#pragma unroll
        for (int nk = 0; nk < 4; ++nk)
#pragma unroll
            for (int r = 0; r < 4; ++r)
                Ps[w][lg * 4 + r][nk * 16 + lr] = (bf16)s[nk][r];
        // rescale O
#pragma unroll
        for (int nd = 0; nd < 4; ++nd)
#pragma unroll
            for (int r = 0; r < 4; ++r) oacc[nd][r] *= alpha[r];
        // PV
        bf16x8 pa0 = ld_frag(&Ps[w][lr][lg * 4]);
        bf16x8 pa1 = ld_frag(&Ps[w][lr][32 + lg * 4]);
#pragma unroll
        for (int nd = 0; nd < 4; ++nd) {
            oacc[nd] = mfma_bf16(pa0, ld_frag(&Vs[nd * 16 + lr][lg * 4]), oacc[nd]);
            oacc[nd] = mfma_bf16(pa1, ld_frag(&Vs[nd * 16 + lr][32 + lg * 4]), oacc[nd]);
        }
    }
    // epilogue: O /= l, clip, write [B,L,H*D] bf16
#pragma unroll
    for (int nd = 0; nd < 4; ++nd) {
#pragma unroll
        for (int r = 0; r < 4; ++r) {
            int qrow = qt * 64 + w * 16 + lg * 4 + r;
            float v = oacc[nd][r] / l_r[r];
            v = fminf(fmaxf(v, -10000.f), 10000.f);
            O[((size_t)(b * SEQ + qrow)) * DIMC + h * HD + nd * 16 + lr] = (bf16)v;
        }
    }
}

extern "C" void kernel_launch(void* const* d_in, const int* in_sizes, int n_in,
                              void* d_out, int out_size, void* d_ws, size_t ws_size,
                              hipStream_t stream) {
    const float* x = (const float*)d_in[0];
    const float* pe = (const float*)d_in[1];
    const float* qkv_w = (const float*)d_in[2];
    const float* q_scale = (const float*)d_in[3];
    const float* k_scale = (const float*)d_in[4];
    const float* proj_w = (const float*)d_in[5];
    const float* proj_b = (const float*)d_in[6];
    float* out = (float*)d_out;
    char* ws = (char*)d_ws;

    // workspace layout (64 MB total)
    bf16* xb = (bf16*)(ws);                              // 8 MB  [4096][1024]
    bf16* wqkv = (bf16*)(ws + (8u << 20));               // 6 MB  [3072][1024]
    bf16* wproj = (bf16*)(ws + (14u << 20));             // 2 MB  [1024][1024]
    bf16* qkvb = (bf16*)(ws + (16u << 20));              // 24 MB [4096][3072]
    bf16* ao = (bf16*)(ws + (16u << 20));                // 8 MB, overlays qkvb (dead)
    bf16* qb = (bf16*)(ws + (40u << 20));                // 8 MB  [B,H,L,D]
    bf16* kb = (bf16*)(ws + (48u << 20));                // 8 MB  [B,H,L,D]
    bf16* vt = (bf16*)(ws + (56u << 20));                // 8 MB  [B,H,D,L]

    k_prep_x<<<4096, 256, 0, stream>>>(x, xb);
    k_cast<<<3072, 256, 0, stream>>>(qkv_w, wqkv);
    k_cast<<<1024, 256, 0, stream>>>(proj_w, wproj);
    // qkv = x_c @ qkv_w^T, nan_to_num, -> bf16
    k_gemm_bt<true, false, true>
        <<<dim3(24, 32), 256, 0, stream>>>(xb, wqkv, (void*)qkvb, nullptr, 3072, 1024);
    k_post<<<dim3(32, HEADS, BATCH), 256, 0, stream>>>(qkvb, pe, q_scale, k_scale, qb, kb, vt);
    k_attn<<<dim3(SEQ / 64, BATCH * HEADS), 256, 0, stream>>>(qb, kb, vt, ao);
    // out = clip(attn_out) @ proj_w^T + proj_b (clip already applied in k_attn)
    k_gemm_bt<false, true, false>
        <<<dim3(8, 32), 256, 0, stream>>>(ao, wproj, (void*)out, proj_b, 1024, 1024);
}

// Round 2
// 174.408 us; speedup vs baseline: 1.2988x; 1.2988x over previous
//
#include <hip/hip_runtime.h>
#include <hip/hip_bf16.h>

#define DIMC 1024
#define HEADS 16
#define HD 64
#define BATCH 2
#define SEQ 2048

typedef __bf16 bf16;
typedef __bf16 bf16x4 __attribute__((ext_vector_type(4)));
typedef __bf16 bf16x8 __attribute__((ext_vector_type(8)));
typedef float f32x4 __attribute__((ext_vector_type(4)));

__device__ inline f32x4 mfma_bf16(bf16x8 a, bf16x8 b, f32x4 c) {
    return __builtin_amdgcn_mfma_f32_16x16x32_bf16(a, b, c, 0, 0, 0);
}

// store 8 bf16 to LDS as two b64 (row strides are 8B- but not 16B-aligned)
__device__ inline void st8(bf16* p, bf16x8 v) {
    *(bf16x4*)p       = *(bf16x4*)&v;
    *(bf16x4*)(p + 4) = *((bf16x4*)&v + 1);
}
// load one MFMA operand fragment: elements 0..3 at k, 4..7 at k+16
__device__ inline bf16x8 ld_frag(const bf16* p) {
    bf16x8 r;
    *(bf16x4*)&r       = *(const bf16x4*)p;
    *((bf16x4*)&r + 1) = *(const bf16x4*)(p + 16);
    return r;
}

// ---------------- prep: sanitize+clip x -> bf16 ----------------
__global__ __launch_bounds__(256) void k_prep_x(const float* __restrict__ x,
                                                bf16* __restrict__ xb) {
    int i = blockIdx.x * 256 + threadIdx.x;
    float4 v = ((const float4*)x)[i];
    float a[4] = {v.x, v.y, v.z, v.w};
    bf16x4 o;
#pragma unroll
    for (int j = 0; j < 4; ++j) {
        float f = a[j];
        f = __builtin_isfinite(f) ? fminf(fmaxf(f, -10000.f), 10000.f) : 0.f;
        o[j] = (bf16)f;
    }
    ((bf16x4*)xb)[i] = o;
}

__global__ __launch_bounds__(256) void k_cast(const float* __restrict__ a,
                                              bf16* __restrict__ o) {
    int i = blockIdx.x * 256 + threadIdx.x;
    float4 v = ((const float4*)a)[i];
    bf16x4 r = {(bf16)v.x, (bf16)v.y, (bf16)v.z, (bf16)v.w};
    ((bf16x4*)o)[i] = r;
}

// ---------------- GEMM: C[M][N] = A[M][K] * Bt[N][K]^T ----------------
// 128x128 tile, 4 waves (2x2), each wave 64x64 = 4x4 frags of 16x16x32 MFMA.
template <bool OUT_BF16, bool BIAS, bool SANITIZE>
__global__ __launch_bounds__(256) void k_gemm_bt(const bf16* __restrict__ A,
                                                 const bf16* __restrict__ Bt,
                                                 void* __restrict__ Cv,
                                                 const float* __restrict__ bias,
                                                 int N, int K) {
    __shared__ bf16 As[128][68];
    __shared__ bf16 Bs[128][68];
    const int t = threadIdx.x;
    const int m0 = blockIdx.y * 128, n0 = blockIdx.x * 128;
    const int w = t >> 6, lane = t & 63;
    const int wm = (w >> 1) * 64, wn = (w & 1) * 64;
    const int lr = lane & 15, lg = lane >> 4;

    f32x4 acc[4][4];
#pragma unroll
    for (int i = 0; i < 4; ++i)
#pragma unroll
        for (int j = 0; j < 4; ++j) acc[i][j] = 0.0f;

    for (int k0 = 0; k0 < K; k0 += 64) {
#pragma unroll
        for (int i = 0; i < 4; ++i) {
            int c = t + i * 256;          // 0..1023
            int r = c >> 3, col = (c & 7) * 8;
            bf16x8 av = *(const bf16x8*)(A + (size_t)(m0 + r) * K + k0 + col);
            bf16x8 bv = *(const bf16x8*)(Bt + (size_t)(n0 + r) * K + k0 + col);
            st8(&As[r][col], av);
            st8(&Bs[r][col], bv);
        }
        __syncthreads();
#pragma unroll
        for (int kk = 0; kk < 2; ++kk) {
            bf16x8 af[4], bfr[4];
#pragma unroll
            for (int mi = 0; mi < 4; ++mi)
                af[mi] = ld_frag(&As[wm + mi * 16 + lr][kk * 32 + lg * 4]);
#pragma unroll
            for (int ni = 0; ni < 4; ++ni)
                bfr[ni] = ld_frag(&Bs[wn + ni * 16 + lr][kk * 32 + lg * 4]);
#pragma unroll
            for (int mi = 0; mi < 4; ++mi)
#pragma unroll
                for (int ni = 0; ni < 4; ++ni)
                    acc[mi][ni] = mfma_bf16(af[mi], bfr[ni], acc[mi][ni]);
        }
        __syncthreads();
    }
    // epilogue; C/D layout: col = lane&15, row = (lane>>4)*4 + reg
#pragma unroll
    for (int mi = 0; mi < 4; ++mi) {
#pragma unroll
        for (int ni = 0; ni < 4; ++ni) {
            int col = n0 + wn + ni * 16 + lr;
            float bval = BIAS ? bias[col] : 0.f;
#pragma unroll
            for (int r = 0; r < 4; ++r) {
                int row = m0 + wm + mi * 16 + lg * 4 + r;
                float v = acc[mi][ni][r];
                if (SANITIZE) v = __builtin_isfinite(v) ? v : 0.f;
                v += bval;
                if (OUT_BF16)
                    ((bf16*)Cv)[(size_t)row * N + col] = (bf16)v;
                else
                    ((float*)Cv)[(size_t)row * N + col] = v;
            }
        }
    }
}

// ---------------- postprocess: rmsnorm + rope, v transpose ----------------
// grid (32 lblocks, 16 heads, 2 batch) x 256 threads
__global__ __launch_bounds__(256) void k_post(const bf16* __restrict__ qkvb,
                                              const float* __restrict__ pe,
                                              const float* __restrict__ q_scale,
                                              const float* __restrict__ k_scale,
                                              bf16* __restrict__ qb,
                                              bf16* __restrict__ kb,
                                              bf16* __restrict__ vt) {
    const int lb = blockIdx.x, h = blockIdx.y, b = blockIdx.z;
    const int t = threadIdx.x;
    const int row = t >> 2, sub = t & 3;  // 64 rows x 4 lanes each
    const int l = lb * 64 + row;
    const int d0 = sub * 16;
    const size_t rowbase = ((size_t)(b * SEQ + l)) * (3 * DIMC) + h * HD;
    const size_t bh = (size_t)(b * HEADS + h);

#pragma unroll
    for (int qk = 0; qk < 2; ++qk) {
        const bf16* src = qkvb + rowbase + qk * DIMC + d0;
        const float* sc = qk ? k_scale : q_scale;
        bf16x8 v0 = *(const bf16x8*)src;
        bf16x8 v1 = *(const bf16x8*)(src + 8);
        float vals[16];
        float ss = 0.f;
#pragma unroll
        for (int j = 0; j < 8; ++j) {
            vals[j] = (float)v0[j];
            vals[8 + j] = (float)v1[j];
        }
#pragma unroll
        for (int j = 0; j < 16; ++j) ss += vals[j] * vals[j];
        ss += __shfl_xor(ss, 1, 64);
        ss += __shfl_xor(ss, 2, 64);
        float rms = rsqrtf(ss * (1.f / 64.f) + 1e-6f);
        // fold attention scale D^-0.5 and log2(e) into q
        const float outscale = qk ? 1.0f : 0.125f * 1.44269504088896340736f;
        bf16 ob[16];
#pragma unroll
        for (int j = 0; j < 16; j += 2) {
            int d = d0 + j;
            float e0 = vals[j] * rms * sc[d];
            float e1 = vals[j + 1] * rms * sc[d + 1];
            float4 pv = *(const float4*)(pe + (size_t)l * 128 + (d >> 1) * 4);
            float o0 = pv.x * e0 + pv.y * e1;
            float o1 = pv.z * e0 + pv.w * e1;
            ob[j] = (bf16)(o0 * outscale);
            ob[j + 1] = (bf16)(o1 * outscale);
        }
        bf16* dst = (qk ? kb : qb) + (bh * SEQ + l) * HD + d0;
        *(bf16x8*)dst = *(bf16x8*)&ob[0];
        *(bf16x8*)(dst + 8) = *(bf16x8*)&ob[8];
    }

    // V: cast + transpose to [B,H,D,L] via LDS
    __shared__ bf16 vlds[64][68];
    {
        const bf16* src = qkvb + rowbase + 2 * DIMC + d0;
        bf16x8 v0 = *(const bf16x8*)src;
        bf16x8 v1 = *(const bf16x8*)(src + 8);
        st8(&vlds[row][d0], v0);
        st8(&vlds[row][d0 + 8], v1);
    }
    __syncthreads();
    {
        const int d = t >> 2, c0 = (t & 3) * 16;
        bf16 ob[16];
#pragma unroll
        for (int j = 0; j < 16; ++j) ob[j] = vlds[c0 + j][d];
        bf16* dst = vt + (bh * HD + d) * SEQ + lb * 64 + c0;
        *(bf16x8*)dst = *(bf16x8*)&ob[0];
        *(bf16x8*)(dst + 8) = *(bf16x8*)&ob[8];
    }
}

// ---------------- flash attention (swapped QK^T, register P, O^T PV) ------
// grid (L/128 q-tiles, B*H), 256 threads = 4 waves, wave w -> q rows w*32..+32
// S^T = mfma(K, Q): lane holds S[q = w*32+sub*16+(lane&15)][key = nk*16+(lane>>4)*4+r]
// -> softmax row is in-lane (16 vals) + 2 shfls; P == A-frag layout for PV,
//    PV computed as O^T = mfma(V^T, P^T) so O columns match lane's m/l.
__global__ __launch_bounds__(256) void k_attn(const bf16* __restrict__ Q,
                                              const bf16* __restrict__ Kb,
                                              const bf16* __restrict__ Vt,
                                              bf16* __restrict__ O) {
    __shared__ bf16 Qs[128][68];
    __shared__ bf16 Ks[64][68];
    __shared__ bf16 Vs[64][68];  // Vt tile: [d][key]
    const int qt = blockIdx.x, bh = blockIdx.y;
    const int b = bh >> 4, h = bh & 15;
    const int t = threadIdx.x, w = t >> 6, lane = t & 63;
    const int lr = lane & 15, lg = lane >> 4;
    const size_t baseQK = (size_t)bh * SEQ * HD;
    const size_t baseVt = (size_t)bh * HD * SEQ;

#pragma unroll
    for (int i = 0; i < 4; ++i) {
        int c = t + i * 256;
        int r = c >> 3, col = (c & 7) * 8;
        bf16x8 v = *(const bf16x8*)(Q + baseQK + (size_t)(qt * 128 + r) * HD + col);
        st8(&Qs[r][col], v);
    }
    __syncthreads();
    bf16x8 qf[2][2];
#pragma unroll
    for (int sub = 0; sub < 2; ++sub) {
        qf[sub][0] = ld_frag(&Qs[w * 32 + sub * 16 + lr][lg * 4]);
        qf[sub][1] = ld_frag(&Qs[w * 32 + sub * 16 + lr][32 + lg * 4]);
    }

    f32x4 oacc[2][4];
#pragma unroll
    for (int s2 = 0; s2 < 2; ++s2)
#pragma unroll
        for (int i = 0; i < 4; ++i) oacc[s2][i] = 0.0f;
    float m_s[2] = {-1e30f, -1e30f}, l_s[2] = {0.f, 0.f};

    for (int kt = 0; kt < SEQ / 64; ++kt) {
        __syncthreads();  // all waves done reading Ks/Vs of prev tile
#pragma unroll
        for (int i = 0; i < 2; ++i) {
            int c = t + i * 256;
            int r = c >> 3, col = (c & 7) * 8;
            bf16x8 kv = *(const bf16x8*)(Kb + baseQK + (size_t)(kt * 64 + r) * HD + col);
            st8(&Ks[r][col], kv);
            bf16x8 vv = *(const bf16x8*)(Vt + baseVt + (size_t)r * SEQ + kt * 64 + col);
            st8(&Vs[r][col], vv);
        }
        __syncthreads();
        bf16x8 kf0[4], kf1[4], vf0[4], vf1[4];
#pragma unroll
        for (int nk = 0; nk < 4; ++nk) {
            kf0[nk] = ld_frag(&Ks[nk * 16 + lr][lg * 4]);
            kf1[nk] = ld_frag(&Ks[nk * 16 + lr][32 + lg * 4]);
            vf0[nk] = ld_frag(&Vs[nk * 16 + lr][lg * 4]);
            vf1[nk] = ld_frag(&Vs[nk * 16 + lr][32 + lg * 4]);
        }
#pragma unroll
        for (int sub = 0; sub < 2; ++sub) {
            f32x4 s[4];
#pragma unroll
            for (int nk = 0; nk < 4; ++nk) {
                f32x4 a = 0.0f;
                a = mfma_bf16(kf0[nk], qf[sub][0], a);
                a = mfma_bf16(kf1[nk], qf[sub][1], a);
                s[nk] = a;
            }
            // row max: 16 in-lane + 2 shfls (q pre-scaled into exp2 domain)
            float tm = fmaxf(fmaxf(s[0][0], s[0][1]), fmaxf(s[0][2], s[0][3]));
#pragma unroll
            for (int nk = 1; nk < 4; ++nk)
                tm = fmaxf(tm, fmaxf(fmaxf(s[nk][0], s[nk][1]),
                                     fmaxf(s[nk][2], s[nk][3])));
            tm = fmaxf(tm, __shfl_xor(tm, 16, 64));
            tm = fmaxf(tm, __shfl_xor(tm, 32, 64));
            float mnew = fmaxf(m_s[sub], tm);
            float alpha = exp2f(m_s[sub] - mnew);
            m_s[sub] = mnew;
            float rs = 0.f;
#pragma unroll
            for (int nk = 0; nk < 4; ++nk)
#pragma unroll
                for (int r2 = 0; r2 < 4; ++r2) {
                    float p = exp2f(s[nk][r2] - mnew);
                    s[nk][r2] = p;
                    rs += p;
                }
            rs += __shfl_xor(rs, 16, 64);
            rs += __shfl_xor(rs, 32, 64);
            l_s[sub] = l_s[sub] * alpha + rs;
            // P already in A-frag layout: pa0 = keys 0..31, pa1 = keys 32..63
            bf16x8 pa0, pa1;
#pragma unroll
            for (int j = 0; j < 4; ++j) {
                pa0[j]     = (bf16)s[0][j];
                pa0[4 + j] = (bf16)s[1][j];
                pa1[j]     = (bf16)s[2][j];
                pa1[4 + j] = (bf16)s[3][j];
            }
#pragma unroll
            for (int nd = 0; nd < 4; ++nd)
#pragma unroll
                for (int r2 = 0; r2 < 4; ++r2) oacc[sub][nd][r2] *= alpha;
#pragma unroll
            for (int nd = 0; nd < 4; ++nd) {
                oacc[sub][nd] = mfma_bf16(vf0[nd], pa0, oacc[sub][nd]);
                oacc[sub][nd] = mfma_bf16(vf1[nd], pa1, oacc[sub][nd]);
            }
        }
    }
    // epilogue: O^T[d][q] regs -> O[b, q, h*64+d], d = nd*16+lg*4+r (4 consecutive)
#pragma unroll
    for (int sub = 0; sub < 2; ++sub) {
        float inv = 1.f / l_s[sub];
        int q = qt * 128 + w * 32 + sub * 16 + lr;
#pragma unroll
        for (int nd = 0; nd < 4; ++nd) {
            bf16x4 ov;
#pragma unroll
            for (int r2 = 0; r2 < 4; ++r2) {
                float v = oacc[sub][nd][r2] * inv;
                v = fminf(fmaxf(v, -10000.f), 10000.f);
                ov[r2] = (bf16)v;
            }
            *(bf16x4*)(O + ((size_t)(b * SEQ + q)) * DIMC + h * HD + nd * 16 + lg * 4) = ov;
        }
    }
}

extern "C" void kernel_launch(void* const* d_in, const int* in_sizes, int n_in,
                              void* d_out, int out_size, void* d_ws, size_t ws_size,
                              hipStream_t stream) {
    const float* x = (const float*)d_in[0];
    const float* pe = (const float*)d_in[1];
    const float* qkv_w = (const float*)d_in[2];
    const float* q_scale = (const float*)d_in[3];
    const float* k_scale = (const float*)d_in[4];
    const float* proj_w = (const float*)d_in[5];
    const float* proj_b = (const float*)d_in[6];
    float* out = (float*)d_out;
    char* ws = (char*)d_ws;

    // workspace layout (64 MB total)
    bf16* xb = (bf16*)(ws);                              // 8 MB  [4096][1024]
    bf16* wqkv = (bf16*)(ws + (8u << 20));               // 6 MB  [3072][1024]
    bf16* wproj = (bf16*)(ws + (14u << 20));             // 2 MB  [1024][1024]
    bf16* qkvb = (bf16*)(ws + (16u << 20));              // 24 MB [4096][3072]
    bf16* ao = (bf16*)(ws + (16u << 20));                // 8 MB, overlays qkvb (dead)
    bf16* qb = (bf16*)(ws + (40u << 20));                // 8 MB  [B,H,L,D]
    bf16* kb = (bf16*)(ws + (48u << 20));                // 8 MB  [B,H,L,D]
    bf16* vt = (bf16*)(ws + (56u << 20));                // 8 MB  [B,H,D,L]

    k_prep_x<<<4096, 256, 0, stream>>>(x, xb);
    k_cast<<<3072, 256, 0, stream>>>(qkv_w, wqkv);
    k_cast<<<1024, 256, 0, stream>>>(proj_w, wproj);
    // qkv = x_c @ qkv_w^T, nan_to_num, -> bf16
    k_gemm_bt<true, false, true>
        <<<dim3(24, 32), 256, 0, stream>>>(xb, wqkv, (void*)qkvb, nullptr, 3072, 1024);
    k_post<<<dim3(32, HEADS, BATCH), 256, 0, stream>>>(qkvb, pe, q_scale, k_scale, qb, kb, vt);
    k_attn<<<dim3(SEQ / 128, BATCH * HEADS), 256, 0, stream>>>(qb, kb, vt, ao);
    // out = clip(attn_out) @ proj_w^T + proj_b (clip already applied in k_attn)
    k_gemm_bt<false, true, false>
        <<<dim3(8, 32), 256, 0, stream>>>(ao, wproj, (void*)out, proj_b, 1024, 1024);
}

// Round 3
// 161.281 us; speedup vs baseline: 1.4046x; 1.0814x over previous
//
#include <hip/hip_runtime.h>
#include <hip/hip_bf16.h>

#define DIMC 1024
#define HEADS 16
#define HD 64
#define BATCH 2
#define SEQ 2048

typedef __bf16 bf16;
typedef __bf16 bf16x4 __attribute__((ext_vector_type(4)));
typedef __bf16 bf16x8 __attribute__((ext_vector_type(8)));
typedef float f32x4 __attribute__((ext_vector_type(4)));

__device__ inline f32x4 mfma_bf16(bf16x8 a, bf16x8 b, f32x4 c) {
    return __builtin_amdgcn_mfma_f32_16x16x32_bf16(a, b, c, 0, 0, 0);
}

// store 8 bf16 to LDS as two b64 (row strides are 8B- but not 16B-aligned)
__device__ inline void st8(bf16* p, bf16x8 v) {
    *(bf16x4*)p       = *(bf16x4*)&v;
    *(bf16x4*)(p + 4) = *((bf16x4*)&v + 1);
}
// load one MFMA operand fragment: elements 0..3 at k, 4..7 at k+16
__device__ inline bf16x8 ld_frag(const bf16* p) {
    bf16x8 r;
    *(bf16x4*)&r       = *(const bf16x4*)p;
    *((bf16x4*)&r + 1) = *(const bf16x4*)(p + 16);
    return r;
}

// ---------------- prep: sanitize+clip x -> bf16 ----------------
__global__ __launch_bounds__(256) void k_prep_x(const float* __restrict__ x,
                                                bf16* __restrict__ xb) {
    int i = blockIdx.x * 256 + threadIdx.x;
    float4 v = ((const float4*)x)[i];
    float a[4] = {v.x, v.y, v.z, v.w};
    bf16x4 o;
#pragma unroll
    for (int j = 0; j < 4; ++j) {
        float f = a[j];
        f = __builtin_isfinite(f) ? fminf(fmaxf(f, -10000.f), 10000.f) : 0.f;
        o[j] = (bf16)f;
    }
    ((bf16x4*)xb)[i] = o;
}

__global__ __launch_bounds__(256) void k_cast(const float* __restrict__ a,
                                              bf16* __restrict__ o) {
    int i = blockIdx.x * 256 + threadIdx.x;
    float4 v = ((const float4*)a)[i];
    bf16x4 r = {(bf16)v.x, (bf16)v.y, (bf16)v.z, (bf16)v.w};
    ((bf16x4*)o)[i] = r;
}

// ---------------- GEMM: C[M][N] = A[M][K] * Bt[N][K]^T ----------------
// 128x128 tile, 4 waves (2x2), each wave 64x64 = 4x4 frags of 16x16x32 MFMA.
template <bool OUT_BF16, bool BIAS, bool SANITIZE>
__global__ __launch_bounds__(256) void k_gemm_bt(const bf16* __restrict__ A,
                                                 const bf16* __restrict__ Bt,
                                                 void* __restrict__ Cv,
                                                 const float* __restrict__ bias,
                                                 int N, int K) {
    __shared__ bf16 As[128][68];
    __shared__ bf16 Bs[128][68];
    const int t = threadIdx.x;
    const int m0 = blockIdx.y * 128, n0 = blockIdx.x * 128;
    const int w = t >> 6, lane = t & 63;
    const int wm = (w >> 1) * 64, wn = (w & 1) * 64;
    const int lr = lane & 15, lg = lane >> 4;

    f32x4 acc[4][4];
#pragma unroll
    for (int i = 0; i < 4; ++i)
#pragma unroll
        for (int j = 0; j < 4; ++j) acc[i][j] = 0.0f;

    for (int k0 = 0; k0 < K; k0 += 64) {
#pragma unroll
        for (int i = 0; i < 4; ++i) {
            int c = t + i * 256;          // 0..1023
            int r = c >> 3, col = (c & 7) * 8;
            bf16x8 av = *(const bf16x8*)(A + (size_t)(m0 + r) * K + k0 + col);
            bf16x8 bv = *(const bf16x8*)(Bt + (size_t)(n0 + r) * K + k0 + col);
            st8(&As[r][col], av);
            st8(&Bs[r][col], bv);
        }
        __syncthreads();
#pragma unroll
        for (int kk = 0; kk < 2; ++kk) {
            bf16x8 af[4], bfr[4];
#pragma unroll
            for (int mi = 0; mi < 4; ++mi)
                af[mi] = ld_frag(&As[wm + mi * 16 + lr][kk * 32 + lg * 4]);
#pragma unroll
            for (int ni = 0; ni < 4; ++ni)
                bfr[ni] = ld_frag(&Bs[wn + ni * 16 + lr][kk * 32 + lg * 4]);
#pragma unroll
            for (int mi = 0; mi < 4; ++mi)
#pragma unroll
                for (int ni = 0; ni < 4; ++ni)
                    acc[mi][ni] = mfma_bf16(af[mi], bfr[ni], acc[mi][ni]);
        }
        __syncthreads();
    }
    // epilogue; C/D layout: col = lane&15, row = (lane>>4)*4 + reg
#pragma unroll
    for (int mi = 0; mi < 4; ++mi) {
#pragma unroll
        for (int ni = 0; ni < 4; ++ni) {
            int col = n0 + wn + ni * 16 + lr;
            float bval = BIAS ? bias[col] : 0.f;
#pragma unroll
            for (int r = 0; r < 4; ++r) {
                int row = m0 + wm + mi * 16 + lg * 4 + r;
                float v = acc[mi][ni][r];
                if (SANITIZE) v = __builtin_isfinite(v) ? v : 0.f;
                v += bval;
                if (OUT_BF16)
                    ((bf16*)Cv)[(size_t)row * N + col] = (bf16)v;
                else
                    ((float*)Cv)[(size_t)row * N + col] = v;
            }
        }
    }
}

// ---------------- postprocess: rmsnorm + rope, v transpose ----------------
// grid (32 lblocks, 16 heads, 2 batch) x 256 threads
__global__ __launch_bounds__(256) void k_post(const bf16* __restrict__ qkvb,
                                              const float* __restrict__ pe,
                                              const float* __restrict__ q_scale,
                                              const float* __restrict__ k_scale,
                                              bf16* __restrict__ qb,
                                              bf16* __restrict__ kb,
                                              bf16* __restrict__ vt) {
    const int lb = blockIdx.x, h = blockIdx.y, b = blockIdx.z;
    const int t = threadIdx.x;
    const int row = t >> 2, sub = t & 3;  // 64 rows x 4 lanes each
    const int l = lb * 64 + row;
    const int d0 = sub * 16;
    const size_t rowbase = ((size_t)(b * SEQ + l)) * (3 * DIMC) + h * HD;
    const size_t bh = (size_t)(b * HEADS + h);

#pragma unroll
    for (int qk = 0; qk < 2; ++qk) {
        const bf16* src = qkvb + rowbase + qk * DIMC + d0;
        const float* sc = qk ? k_scale : q_scale;
        bf16x8 v0 = *(const bf16x8*)src;
        bf16x8 v1 = *(const bf16x8*)(src + 8);
        float vals[16];
        float ss = 0.f;
#pragma unroll
        for (int j = 0; j < 8; ++j) {
            vals[j] = (float)v0[j];
            vals[8 + j] = (float)v1[j];
        }
#pragma unroll
        for (int j = 0; j < 16; ++j) ss += vals[j] * vals[j];
        ss += __shfl_xor(ss, 1, 64);
        ss += __shfl_xor(ss, 2, 64);
        float rms = rsqrtf(ss * (1.f / 64.f) + 1e-6f);
        // fold attention scale D^-0.5 and log2(e) into q
        const float outscale = qk ? 1.0f : 0.125f * 1.44269504088896340736f;
        bf16 ob[16];
#pragma unroll
        for (int j = 0; j < 16; j += 2) {
            int d = d0 + j;
            float e0 = vals[j] * rms * sc[d];
            float e1 = vals[j + 1] * rms * sc[d + 1];
            float4 pv = *(const float4*)(pe + (size_t)l * 128 + (d >> 1) * 4);
            float o0 = pv.x * e0 + pv.y * e1;
            float o1 = pv.z * e0 + pv.w * e1;
            ob[j] = (bf16)(o0 * outscale);
            ob[j + 1] = (bf16)(o1 * outscale);
        }
        bf16* dst = (qk ? kb : qb) + (bh * SEQ + l) * HD + d0;
        *(bf16x8*)dst = *(bf16x8*)&ob[0];
        *(bf16x8*)(dst + 8) = *(bf16x8*)&ob[8];
    }

    // V: cast + transpose to [B,H,D,L] via LDS
    __shared__ bf16 vlds[64][68];
    {
        const bf16* src = qkvb + rowbase + 2 * DIMC + d0;
        bf16x8 v0 = *(const bf16x8*)src;
        bf16x8 v1 = *(const bf16x8*)(src + 8);
        st8(&vlds[row][d0], v0);
        st8(&vlds[row][d0 + 8], v1);
    }
    __syncthreads();
    {
        const int d = t >> 2, c0 = (t & 3) * 16;
        bf16 ob[16];
#pragma unroll
        for (int j = 0; j < 16; ++j) ob[j] = vlds[c0 + j][d];
        bf16* dst = vt + (bh * HD + d) * SEQ + lb * 64 + c0;
        *(bf16x8*)dst = *(bf16x8*)&ob[0];
        *(bf16x8*)(dst + 8) = *(bf16x8*)&ob[8];
    }
}

// ---------------- flash attention (swapped QK^T, register P, O^T PV) ------
// grid (L/128 q-tiles, B*H), 512 threads = 8 waves, wave w -> q rows w*16..+16
// S^T = mfma(K, Q): lane holds S[q = w*16+(lane&15)][key = nk*16+(lane>>4)*4+r]
// -> softmax row is in-lane (16 vals) + 2 shfls; P == A-frag layout for PV,
//    PV computed as O^T = mfma(V^T, P^T) so O columns match lane's m/l.
// K/V double-buffered; next tile's global loads issued before compute (T14).
__global__ __launch_bounds__(512) void k_attn(const bf16* __restrict__ Q,
                                              const bf16* __restrict__ Kb,
                                              const bf16* __restrict__ Vt,
                                              bf16* __restrict__ O) {
    __shared__ bf16 Qs[128][68];
    __shared__ bf16 Ks[2][64][68];
    __shared__ bf16 Vs[2][64][68];  // Vt tile: [d][key]
    const int qt = blockIdx.x, bh = blockIdx.y;
    const int b = bh >> 4, h = bh & 15;
    const int t = threadIdx.x, w = t >> 6, lane = t & 63;
    const int lr = lane & 15, lg = lane >> 4;
    const size_t baseQK = (size_t)bh * SEQ * HD;
    const size_t baseVt = (size_t)bh * HD * SEQ;

    const int sr = t >> 3, scol = (t & 7) * 8;  // staging coords (512 chunks)
#pragma unroll
    for (int i = 0; i < 2; ++i) {
        int c = t + i * 512;
        int r = c >> 3, col = (c & 7) * 8;
        bf16x8 v = *(const bf16x8*)(Q + baseQK + (size_t)(qt * 128 + r) * HD + col);
        st8(&Qs[r][col], v);
    }
    // stage K/V tile 0
    {
        bf16x8 kv = *(const bf16x8*)(Kb + baseQK + (size_t)sr * HD + scol);
        bf16x8 vv = *(const bf16x8*)(Vt + baseVt + (size_t)sr * SEQ + scol);
        st8(&Ks[0][sr][scol], kv);
        st8(&Vs[0][sr][scol], vv);
    }
    __syncthreads();
    bf16x8 qf0 = ld_frag(&Qs[w * 16 + lr][lg * 4]);
    bf16x8 qf1 = ld_frag(&Qs[w * 16 + lr][32 + lg * 4]);

    f32x4 oacc[4];
#pragma unroll
    for (int i = 0; i < 4; ++i) oacc[i] = 0.0f;
    float m_s = -1e30f, l_s = 0.f;

    int cur = 0;
    for (int kt = 0; kt < SEQ / 64; ++kt) {
        // issue next tile's global loads early (latency hidden under compute)
        bf16x8 kreg, vreg;
        const bool pf = (kt + 1) < SEQ / 64;
        if (pf) {
            kreg = *(const bf16x8*)(Kb + baseQK + (size_t)((kt + 1) * 64 + sr) * HD + scol);
            vreg = *(const bf16x8*)(Vt + baseVt + (size_t)sr * SEQ + (kt + 1) * 64 + scol);
        }
        // QK^T on current tile
        f32x4 s[4];
#pragma unroll
        for (int nk = 0; nk < 4; ++nk) {
            f32x4 a = 0.0f;
            a = mfma_bf16(ld_frag(&Ks[cur][nk * 16 + lr][lg * 4]), qf0, a);
            a = mfma_bf16(ld_frag(&Ks[cur][nk * 16 + lr][32 + lg * 4]), qf1, a);
            s[nk] = a;
        }
        // row max: 16 in-lane + 2 shfls (q pre-scaled into exp2 domain)
        float tm = fmaxf(fmaxf(s[0][0], s[0][1]), fmaxf(s[0][2], s[0][3]));
#pragma unroll
        for (int nk = 1; nk < 4; ++nk)
            tm = fmaxf(tm, fmaxf(fmaxf(s[nk][0], s[nk][1]),
                                 fmaxf(s[nk][2], s[nk][3])));
        tm = fmaxf(tm, __shfl_xor(tm, 16, 64));
        tm = fmaxf(tm, __shfl_xor(tm, 32, 64));
        float mnew = fmaxf(m_s, tm);
        float alpha = exp2f(m_s - mnew);
        m_s = mnew;
        float rs = 0.f;
#pragma unroll
        for (int nk = 0; nk < 4; ++nk)
#pragma unroll
            for (int r2 = 0; r2 < 4; ++r2) {
                float p = exp2f(s[nk][r2] - mnew);
                s[nk][r2] = p;
                rs += p;
            }
        rs += __shfl_xor(rs, 16, 64);
        rs += __shfl_xor(rs, 32, 64);
        l_s = l_s * alpha + rs;
        // P already in A-frag layout: pa0 = keys 0..31, pa1 = keys 32..63
        bf16x8 pa0, pa1;
#pragma unroll
        for (int j = 0; j < 4; ++j) {
            pa0[j]     = (bf16)s[0][j];
            pa0[4 + j] = (bf16)s[1][j];
            pa1[j]     = (bf16)s[2][j];
            pa1[4 + j] = (bf16)s[3][j];
        }
#pragma unroll
        for (int nd = 0; nd < 4; ++nd)
#pragma unroll
            for (int r2 = 0; r2 < 4; ++r2) oacc[nd][r2] *= alpha;
#pragma unroll
        for (int nd = 0; nd < 4; ++nd) {
            oacc[nd] = mfma_bf16(ld_frag(&Vs[cur][nd * 16 + lr][lg * 4]), pa0, oacc[nd]);
            oacc[nd] = mfma_bf16(ld_frag(&Vs[cur][nd * 16 + lr][32 + lg * 4]), pa1, oacc[nd]);
        }
        // write prefetched tile into the other buffer (readers synced at kt-1's barrier)
        if (pf) {
            st8(&Ks[cur ^ 1][sr][scol], kreg);
            st8(&Vs[cur ^ 1][sr][scol], vreg);
        }
        __syncthreads();
        cur ^= 1;
    }
    // epilogue: O^T[d][q] regs -> O[b, q, h*64+d], d = nd*16+lg*4+r (4 consecutive)
    {
        float inv = 1.f / l_s;
        int q = qt * 128 + w * 16 + lr;
#pragma unroll
        for (int nd = 0; nd < 4; ++nd) {
            bf16x4 ov;
#pragma unroll
            for (int r2 = 0; r2 < 4; ++r2) {
                float v = oacc[nd][r2] * inv;
                v = fminf(fmaxf(v, -10000.f), 10000.f);
                ov[r2] = (bf16)v;
            }
            *(bf16x4*)(O + ((size_t)(b * SEQ + q)) * DIMC + h * HD + nd * 16 + lg * 4) = ov;
        }
    }
}

extern "C" void kernel_launch(void* const* d_in, const int* in_sizes, int n_in,
                              void* d_out, int out_size, void* d_ws, size_t ws_size,
                              hipStream_t stream) {
    const float* x = (const float*)d_in[0];
    const float* pe = (const float*)d_in[1];
    const float* qkv_w = (const float*)d_in[2];
    const float* q_scale = (const float*)d_in[3];
    const float* k_scale = (const float*)d_in[4];
    const float* proj_w = (const float*)d_in[5];
    const float* proj_b = (const float*)d_in[6];
    float* out = (float*)d_out;
    char* ws = (char*)d_ws;

    // workspace layout (64 MB total)
    bf16* xb = (bf16*)(ws);                              // 8 MB  [4096][1024]
    bf16* wqkv = (bf16*)(ws + (8u << 20));               // 6 MB  [3072][1024]
    bf16* wproj = (bf16*)(ws + (14u << 20));             // 2 MB  [1024][1024]
    bf16* qkvb = (bf16*)(ws + (16u << 20));              // 24 MB [4096][3072]
    bf16* ao = (bf16*)(ws + (16u << 20));                // 8 MB, overlays qkvb (dead)
    bf16* qb = (bf16*)(ws + (40u << 20));                // 8 MB  [B,H,L,D]
    bf16* kb = (bf16*)(ws + (48u << 20));                // 8 MB  [B,H,L,D]
    bf16* vt = (bf16*)(ws + (56u << 20));                // 8 MB  [B,H,D,L]

    k_prep_x<<<4096, 256, 0, stream>>>(x, xb);
    k_cast<<<3072, 256, 0, stream>>>(qkv_w, wqkv);
    k_cast<<<1024, 256, 0, stream>>>(proj_w, wproj);
    // qkv = x_c @ qkv_w^T, nan_to_num, -> bf16
    k_gemm_bt<true, false, true>
        <<<dim3(24, 32), 256, 0, stream>>>(xb, wqkv, (void*)qkvb, nullptr, 3072, 1024);
    k_post<<<dim3(32, HEADS, BATCH), 256, 0, stream>>>(qkvb, pe, q_scale, k_scale, qb, kb, vt);
    k_attn<<<dim3(SEQ / 128, BATCH * HEADS), 512, 0, stream>>>(qb, kb, vt, ao);
    // out = clip(attn_out) @ proj_w^T + proj_b (clip already applied in k_attn)
    k_gemm_bt<false, true, false>
        <<<dim3(8, 32), 256, 0, stream>>>(ao, wproj, (void*)out, proj_b, 1024, 1024);
}

// Round 4
// 156.343 us; speedup vs baseline: 1.4489x; 1.0316x over previous
//
#include <hip/hip_runtime.h>
#include <hip/hip_bf16.h>

#define DIMC 1024
#define HEADS 16
#define HD 64
#define BATCH 2
#define SEQ 2048

typedef __bf16 bf16;
typedef __bf16 bf16x4 __attribute__((ext_vector_type(4)));
typedef __bf16 bf16x8 __attribute__((ext_vector_type(8)));
typedef float f32x4 __attribute__((ext_vector_type(4)));

__device__ inline f32x4 mfma_bf16(bf16x8 a, bf16x8 b, f32x4 c) {
    return __builtin_amdgcn_mfma_f32_16x16x32_bf16(a, b, c, 0, 0, 0);
}

// store 8 bf16 to LDS as two b64 (row strides are 8B- but not 16B-aligned)
__device__ inline void st8(bf16* p, bf16x8 v) {
    *(bf16x4*)p       = *(bf16x4*)&v;
    *(bf16x4*)(p + 4) = *((bf16x4*)&v + 1);
}
// load one MFMA operand fragment: elements 0..3 at k, 4..7 at k+16
__device__ inline bf16x8 ld_frag(const bf16* p) {
    bf16x8 r;
    *(bf16x4*)&r       = *(const bf16x4*)p;
    *((bf16x4*)&r + 1) = *(const bf16x4*)(p + 16);
    return r;
}

// ---------------- prep: sanitize+clip x -> bf16 ----------------
__global__ __launch_bounds__(256) void k_prep_x(const float* __restrict__ x,
                                                bf16* __restrict__ xb) {
    int i = blockIdx.x * 256 + threadIdx.x;
    float4 v = ((const float4*)x)[i];
    float a[4] = {v.x, v.y, v.z, v.w};
    bf16x4 o;
#pragma unroll
    for (int j = 0; j < 4; ++j) {
        float f = a[j];
        f = __builtin_isfinite(f) ? fminf(fmaxf(f, -10000.f), 10000.f) : 0.f;
        o[j] = (bf16)f;
    }
    ((bf16x4*)xb)[i] = o;
}

__global__ __launch_bounds__(256) void k_cast(const float* __restrict__ a,
                                              bf16* __restrict__ o) {
    int i = blockIdx.x * 256 + threadIdx.x;
    float4 v = ((const float4*)a)[i];
    bf16x4 r = {(bf16)v.x, (bf16)v.y, (bf16)v.z, (bf16)v.w};
    ((bf16x4*)o)[i] = r;
}

// ---------------- GEMM: C[M][N] = A[M][K] * Bt[N][K]^T ----------------
// 128x128 tile, 4 waves (2x2), each wave 64x64 = 4x4 frags of 16x16x32 MFMA.
template <bool OUT_BF16, bool BIAS, bool SANITIZE>
__global__ __launch_bounds__(256) void k_gemm_bt(const bf16* __restrict__ A,
                                                 const bf16* __restrict__ Bt,
                                                 void* __restrict__ Cv,
                                                 const float* __restrict__ bias,
                                                 int N, int K) {
    __shared__ bf16 As[128][68];
    __shared__ bf16 Bs[128][68];
    const int t = threadIdx.x;
    const int m0 = blockIdx.y * 128, n0 = blockIdx.x * 128;
    const int w = t >> 6, lane = t & 63;
    const int wm = (w >> 1) * 64, wn = (w & 1) * 64;
    const int lr = lane & 15, lg = lane >> 4;

    f32x4 acc[4][4];
#pragma unroll
    for (int i = 0; i < 4; ++i)
#pragma unroll
        for (int j = 0; j < 4; ++j) acc[i][j] = 0.0f;

    for (int k0 = 0; k0 < K; k0 += 64) {
#pragma unroll
        for (int i = 0; i < 4; ++i) {
            int c = t + i * 256;          // 0..1023
            int r = c >> 3, col = (c & 7) * 8;
            bf16x8 av = *(const bf16x8*)(A + (size_t)(m0 + r) * K + k0 + col);
            bf16x8 bv = *(const bf16x8*)(Bt + (size_t)(n0 + r) * K + k0 + col);
            st8(&As[r][col], av);
            st8(&Bs[r][col], bv);
        }
        __syncthreads();
#pragma unroll
        for (int kk = 0; kk < 2; ++kk) {
            bf16x8 af[4], bfr[4];
#pragma unroll
            for (int mi = 0; mi < 4; ++mi)
                af[mi] = ld_frag(&As[wm + mi * 16 + lr][kk * 32 + lg * 4]);
#pragma unroll
            for (int ni = 0; ni < 4; ++ni)
                bfr[ni] = ld_frag(&Bs[wn + ni * 16 + lr][kk * 32 + lg * 4]);
#pragma unroll
            for (int mi = 0; mi < 4; ++mi)
#pragma unroll
                for (int ni = 0; ni < 4; ++ni)
                    acc[mi][ni] = mfma_bf16(af[mi], bfr[ni], acc[mi][ni]);
        }
        __syncthreads();
    }
    // epilogue; C/D layout: col = lane&15, row = (lane>>4)*4 + reg
#pragma unroll
    for (int mi = 0; mi < 4; ++mi) {
#pragma unroll
        for (int ni = 0; ni < 4; ++ni) {
            int col = n0 + wn + ni * 16 + lr;
            float bval = BIAS ? bias[col] : 0.f;
#pragma unroll
            for (int r = 0; r < 4; ++r) {
                int row = m0 + wm + mi * 16 + lg * 4 + r;
                float v = acc[mi][ni][r];
                if (SANITIZE) v = __builtin_isfinite(v) ? v : 0.f;
                v += bval;
                if (OUT_BF16)
                    ((bf16*)Cv)[(size_t)row * N + col] = (bf16)v;
                else
                    ((float*)Cv)[(size_t)row * N + col] = v;
            }
        }
    }
}

// ---------------- postprocess: rmsnorm + rope, v transpose ----------------
// grid (32 lblocks, 16 heads, 2 batch) x 256 threads
__global__ __launch_bounds__(256) void k_post(const bf16* __restrict__ qkvb,
                                              const float* __restrict__ pe,
                                              const float* __restrict__ q_scale,
                                              const float* __restrict__ k_scale,
                                              bf16* __restrict__ qb,
                                              bf16* __restrict__ kb,
                                              bf16* __restrict__ vt) {
    const int lb = blockIdx.x, h = blockIdx.y, b = blockIdx.z;
    const int t = threadIdx.x;
    const int row = t >> 2, sub = t & 3;  // 64 rows x 4 lanes each
    const int l = lb * 64 + row;
    const int d0 = sub * 16;
    const size_t rowbase = ((size_t)(b * SEQ + l)) * (3 * DIMC) + h * HD;
    const size_t bh = (size_t)(b * HEADS + h);

#pragma unroll
    for (int qk = 0; qk < 2; ++qk) {
        const bf16* src = qkvb + rowbase + qk * DIMC + d0;
        const float* sc = qk ? k_scale : q_scale;
        bf16x8 v0 = *(const bf16x8*)src;
        bf16x8 v1 = *(const bf16x8*)(src + 8);
        float vals[16];
        float ss = 0.f;
#pragma unroll
        for (int j = 0; j < 8; ++j) {
            vals[j] = (float)v0[j];
            vals[8 + j] = (float)v1[j];
        }
#pragma unroll
        for (int j = 0; j < 16; ++j) ss += vals[j] * vals[j];
        ss += __shfl_xor(ss, 1, 64);
        ss += __shfl_xor(ss, 2, 64);
        float rms = rsqrtf(ss * (1.f / 64.f) + 1e-6f);
        // fold attention scale D^-0.5 and log2(e) into q
        const float outscale = qk ? 1.0f : 0.125f * 1.44269504088896340736f;
        bf16 ob[16];
#pragma unroll
        for (int j = 0; j < 16; j += 2) {
            int d = d0 + j;
            float e0 = vals[j] * rms * sc[d];
            float e1 = vals[j + 1] * rms * sc[d + 1];
            float4 pv = *(const float4*)(pe + (size_t)l * 128 + (d >> 1) * 4);
            float o0 = pv.x * e0 + pv.y * e1;
            float o1 = pv.z * e0 + pv.w * e1;
            ob[j] = (bf16)(o0 * outscale);
            ob[j + 1] = (bf16)(o1 * outscale);
        }
        bf16* dst = (qk ? kb : qb) + (bh * SEQ + l) * HD + d0;
        *(bf16x8*)dst = *(bf16x8*)&ob[0];
        *(bf16x8*)(dst + 8) = *(bf16x8*)&ob[8];
    }

    // V: cast + transpose to [B,H,D,L] via LDS
    __shared__ bf16 vlds[64][68];
    {
        const bf16* src = qkvb + rowbase + 2 * DIMC + d0;
        bf16x8 v0 = *(const bf16x8*)src;
        bf16x8 v1 = *(const bf16x8*)(src + 8);
        st8(&vlds[row][d0], v0);
        st8(&vlds[row][d0 + 8], v1);
    }
    __syncthreads();
    {
        const int d = t >> 2, c0 = (t & 3) * 16;
        bf16 ob[16];
#pragma unroll
        for (int j = 0; j < 16; ++j) ob[j] = vlds[c0 + j][d];
        bf16* dst = vt + (bh * HD + d) * SEQ + lb * 64 + c0;
        *(bf16x8*)dst = *(bf16x8*)&ob[0];
        *(bf16x8*)(dst + 8) = *(bf16x8*)&ob[8];
    }
}

// ---------------- flash attention (swapped QK^T, register P, O^T PV) ------
// grid (L/128 q-tiles, B*H), 512 threads = 8 waves, wave w -> q rows w*16..+16
// S^T = mfma(K, Q): lane holds S[q = w*16+(lane&15)][key = nk*16+(lane>>4)*4+r]
// -> softmax row is in-lane (16 vals) + 2 shfls; P == A-frag layout for PV,
//    PV computed as O^T = mfma(V^T, P^T) so O columns match lane's m/l.
// l computed via mfma(ones, P) (row-sum lands in the same lane as the q row);
// defer-max (THR=8 in exp2 domain) skips the rescale pass on most tiles.
// K/V double-buffered; next tile's global loads issued before compute (T14).
__global__ __launch_bounds__(512) void k_attn(const bf16* __restrict__ Q,
                                              const bf16* __restrict__ Kb,
                                              const bf16* __restrict__ Vt,
                                              bf16* __restrict__ O) {
    __shared__ bf16 Ks[2][64][68];
    __shared__ bf16 Vs[2][64][68];  // Vt tile: [d][key]
    const int qt = blockIdx.x, bh = blockIdx.y;
    const int b = bh >> 4, h = bh & 15;
    const int t = threadIdx.x, w = t >> 6, lane = t & 63;
    const int lr = lane & 15, lg = lane >> 4;
    const size_t baseQK = (size_t)bh * SEQ * HD;
    const size_t baseVt = (size_t)bh * HD * SEQ;

    // Q fragments straight from global (lane-private; 4 x 8B loads)
    const bf16* qp = Q + baseQK + (size_t)(qt * 128 + w * 16 + lr) * HD;
    bf16x8 qf0 = ld_frag(qp + lg * 4);
    bf16x8 qf1 = ld_frag(qp + 32 + lg * 4);

    const int sr = t >> 3, scol = (t & 7) * 8;  // staging coords (512 chunks)
    // stage K/V tile 0
    {
        bf16x8 kv = *(const bf16x8*)(Kb + baseQK + (size_t)sr * HD + scol);
        bf16x8 vv = *(const bf16x8*)(Vt + baseVt + (size_t)sr * SEQ + scol);
        st8(&Ks[0][sr][scol], kv);
        st8(&Vs[0][sr][scol], vv);
    }
    __syncthreads();

    bf16x8 ones;
#pragma unroll
    for (int j = 0; j < 8; ++j) ones[j] = (bf16)1.0f;

    f32x4 oacc[4];
#pragma unroll
    for (int i = 0; i < 4; ++i) oacc[i] = 0.0f;
    f32x4 lacc = 0.0f;
    float m_s = -1e30f;

    int cur = 0;
    for (int kt = 0; kt < SEQ / 64; ++kt) {
        // issue next tile's global loads early (latency hidden under compute)
        bf16x8 kreg, vreg;
        const bool pf = (kt + 1) < SEQ / 64;
        if (pf) {
            kreg = *(const bf16x8*)(Kb + baseQK + (size_t)((kt + 1) * 64 + sr) * HD + scol);
            vreg = *(const bf16x8*)(Vt + baseVt + (size_t)sr * SEQ + (kt + 1) * 64 + scol);
        }
        // QK^T on current tile
        __builtin_amdgcn_s_setprio(1);
        f32x4 s[4];
#pragma unroll
        for (int nk = 0; nk < 4; ++nk) {
            f32x4 a = 0.0f;
            a = mfma_bf16(ld_frag(&Ks[cur][nk * 16 + lr][lg * 4]), qf0, a);
            a = mfma_bf16(ld_frag(&Ks[cur][nk * 16 + lr][32 + lg * 4]), qf1, a);
            s[nk] = a;
        }
        __builtin_amdgcn_s_setprio(0);
        // row max: 16 in-lane + 2 shfls (q pre-scaled into exp2 domain)
        float tm = fmaxf(fmaxf(s[0][0], s[0][1]), fmaxf(s[0][2], s[0][3]));
#pragma unroll
        for (int nk = 1; nk < 4; ++nk)
            tm = fmaxf(tm, fmaxf(fmaxf(s[nk][0], s[nk][1]),
                                 fmaxf(s[nk][2], s[nk][3])));
        tm = fmaxf(tm, __shfl_xor(tm, 16, 64));
        tm = fmaxf(tm, __shfl_xor(tm, 32, 64));
        // defer-max: only rescale when some row grew past THR=8
        if (!__all(tm <= m_s + 8.f)) {
            float mnew = fmaxf(m_s, tm);
            float alpha = exp2f(m_s - mnew);
            m_s = mnew;
#pragma unroll
            for (int nd = 0; nd < 4; ++nd)
#pragma unroll
                for (int r2 = 0; r2 < 4; ++r2) oacc[nd][r2] *= alpha;
#pragma unroll
            for (int r2 = 0; r2 < 4; ++r2) lacc[r2] *= alpha;
        }
        // P (bounded by 2^8) packed straight into A-frag layout
        bf16x8 pa0, pa1;
#pragma unroll
        for (int j = 0; j < 4; ++j) {
            pa0[j]     = (bf16)exp2f(s[0][j] - m_s);
            pa0[4 + j] = (bf16)exp2f(s[1][j] - m_s);
            pa1[j]     = (bf16)exp2f(s[2][j] - m_s);
            pa1[4 + j] = (bf16)exp2f(s[3][j] - m_s);
        }
        __builtin_amdgcn_s_setprio(1);
        // l row-sum via ones-MFMA (lands in col q = lane&15, all regs equal)
        lacc = mfma_bf16(ones, pa0, lacc);
        lacc = mfma_bf16(ones, pa1, lacc);
#pragma unroll
        for (int nd = 0; nd < 4; ++nd) {
            oacc[nd] = mfma_bf16(ld_frag(&Vs[cur][nd * 16 + lr][lg * 4]), pa0, oacc[nd]);
            oacc[nd] = mfma_bf16(ld_frag(&Vs[cur][nd * 16 + lr][32 + lg * 4]), pa1, oacc[nd]);
        }
        __builtin_amdgcn_s_setprio(0);
        // write prefetched tile into the other buffer (readers synced at kt-1's barrier)
        if (pf) {
            st8(&Ks[cur ^ 1][sr][scol], kreg);
            st8(&Vs[cur ^ 1][sr][scol], vreg);
        }
        __syncthreads();
        cur ^= 1;
    }
    // epilogue: O^T[d][q] regs -> O[b, q, h*64+d], d = nd*16+lg*4+r (4 consecutive)
    {
        float inv = 1.f / lacc[0];
        int q = qt * 128 + w * 16 + lr;
#pragma unroll
        for (int nd = 0; nd < 4; ++nd) {
            bf16x4 ov;
#pragma unroll
            for (int r2 = 0; r2 < 4; ++r2) {
                float v = oacc[nd][r2] * inv;
                v = fminf(fmaxf(v, -10000.f), 10000.f);
                ov[r2] = (bf16)v;
            }
            *(bf16x4*)(O + ((size_t)(b * SEQ + q)) * DIMC + h * HD + nd * 16 + lg * 4) = ov;
        }
    }
}

extern "C" void kernel_launch(void* const* d_in, const int* in_sizes, int n_in,
                              void* d_out, int out_size, void* d_ws, size_t ws_size,
                              hipStream_t stream) {
    const float* x = (const float*)d_in[0];
    const float* pe = (const float*)d_in[1];
    const float* qkv_w = (const float*)d_in[2];
    const float* q_scale = (const float*)d_in[3];
    const float* k_scale = (const float*)d_in[4];
    const float* proj_w = (const float*)d_in[5];
    const float* proj_b = (const float*)d_in[6];
    float* out = (float*)d_out;
    char* ws = (char*)d_ws;

    // workspace layout (64 MB total)
    bf16* xb = (bf16*)(ws);                              // 8 MB  [4096][1024]
    bf16* wqkv = (bf16*)(ws + (8u << 20));               // 6 MB  [3072][1024]
    bf16* wproj = (bf16*)(ws + (14u << 20));             // 2 MB  [1024][1024]
    bf16* qkvb = (bf16*)(ws + (16u << 20));              // 24 MB [4096][3072]
    bf16* ao = (bf16*)(ws + (16u << 20));                // 8 MB, overlays qkvb (dead)
    bf16* qb = (bf16*)(ws + (40u << 20));                // 8 MB  [B,H,L,D]
    bf16* kb = (bf16*)(ws + (48u << 20));                // 8 MB  [B,H,L,D]
    bf16* vt = (bf16*)(ws + (56u << 20));                // 8 MB  [B,H,D,L]

    k_prep_x<<<4096, 256, 0, stream>>>(x, xb);
    k_cast<<<3072, 256, 0, stream>>>(qkv_w, wqkv);
    k_cast<<<1024, 256, 0, stream>>>(proj_w, wproj);
    // qkv = x_c @ qkv_w^T, nan_to_num, -> bf16
    k_gemm_bt<true, false, true>
        <<<dim3(24, 32), 256, 0, stream>>>(xb, wqkv, (void*)qkvb, nullptr, 3072, 1024);
    k_post<<<dim3(32, HEADS, BATCH), 256, 0, stream>>>(qkvb, pe, q_scale, k_scale, qb, kb, vt);
    k_attn<<<dim3(SEQ / 128, BATCH * HEADS), 512, 0, stream>>>(qb, kb, vt, ao);
    // out = clip(attn_out) @ proj_w^T + proj_b (clip already applied in k_attn)
    k_gemm_bt<false, true, false>
        <<<dim3(8, 32), 256, 0, stream>>>(ao, wproj, (void*)out, proj_b, 1024, 1024);
}

// Round 5
// 156.190 us; speedup vs baseline: 1.4503x; 1.0010x over previous
//
#include <hip/hip_runtime.h>
#include <hip/hip_bf16.h>

#define DIMC 1024
#define HEADS 16
#define HD 64
#define BATCH 2
#define SEQ 2048

typedef __bf16 bf16;
typedef __bf16 bf16x4 __attribute__((ext_vector_type(4)));
typedef __bf16 bf16x8 __attribute__((ext_vector_type(8)));
typedef float f32x4 __attribute__((ext_vector_type(4)));

typedef const __attribute__((address_space(1))) void* gas_t;
typedef __attribute__((address_space(3))) void* las_t;

__device__ inline f32x4 mfma_bf16(bf16x8 a, bf16x8 b, f32x4 c) {
    return __builtin_amdgcn_mfma_f32_16x16x32_bf16(a, b, c, 0, 0, 0);
}

// store 8 bf16 to LDS as two b64 (row strides are 8B- but not 16B-aligned)
__device__ inline void st8(bf16* p, bf16x8 v) {
    *(bf16x4*)p       = *(bf16x4*)&v;
    *(bf16x4*)(p + 4) = *((bf16x4*)&v + 1);
}
// load one MFMA operand fragment: elements 0..3 at k, 4..7 at k+16
__device__ inline bf16x8 ld_frag(const bf16* p) {
    bf16x8 r;
    *(bf16x4*)&r       = *(const bf16x4*)p;
    *((bf16x4*)&r + 1) = *(const bf16x4*)(p + 16);
    return r;
}
// fragment read from a linear [*, 64] LDS tile with XOR-swizzled chunks:
// rowp = &tile[row*64]; cb = byte col (kk*64 + lg*8); sw = (row&7)<<4
__device__ inline bf16x8 ld_frag_s(const bf16* rowp, int cb, int sw) {
    bf16x8 r;
    *(bf16x4*)&r       = *(const bf16x4*)((const char*)rowp + ((cb) ^ sw));
    *((bf16x4*)&r + 1) = *(const bf16x4*)((const char*)rowp + ((cb + 32) ^ sw));
    return r;
}

// ---------------- prep: sanitize+clip x -> bf16 ----------------
__global__ __launch_bounds__(256) void k_prep_x(const float* __restrict__ x,
                                                bf16* __restrict__ xb) {
    int i = blockIdx.x * 256 + threadIdx.x;
    float4 v = ((const float4*)x)[i];
    float a[4] = {v.x, v.y, v.z, v.w};
    bf16x4 o;
#pragma unroll
    for (int j = 0; j < 4; ++j) {
        float f = a[j];
        f = __builtin_isfinite(f) ? fminf(fmaxf(f, -10000.f), 10000.f) : 0.f;
        o[j] = (bf16)f;
    }
    ((bf16x4*)xb)[i] = o;
}

__global__ __launch_bounds__(256) void k_cast(const float* __restrict__ a,
                                              bf16* __restrict__ o) {
    int i = blockIdx.x * 256 + threadIdx.x;
    float4 v = ((const float4*)a)[i];
    bf16x4 r = {(bf16)v.x, (bf16)v.y, (bf16)v.z, (bf16)v.w};
    ((bf16x4*)o)[i] = r;
}

// ---------------- GEMM: C[M][N] = A[M][K] * Bt[N][K]^T ----------------
// m97 structure: 128x128 tile, BK=64, linear LDS + global_load_lds width=16,
// XOR-swizzled chunks (pre-swizzled global source, swizzled ds_read).
// 4 waves (2x2), each wave 64x64 = 4x4 frags of 16x16x32 MFMA.
template <bool OUT_BF16, bool BIAS, bool SANITIZE>
__global__ __launch_bounds__(256) void k_gemm_bt(const bf16* __restrict__ A,
                                                 const bf16* __restrict__ Bt,
                                                 void* __restrict__ Cv,
                                                 const float* __restrict__ bias,
                                                 int N, int K) {
    __shared__ alignas(16) bf16 As[128 * 64];
    __shared__ alignas(16) bf16 Bs[128 * 64];
    const int t = threadIdx.x;
    const int m0 = blockIdx.y * 128, n0 = blockIdx.x * 128;
    const int w = t >> 6, lane = t & 63;
    const int wm = (w >> 1) * 64, wn = (w & 1) * 64;
    const int lr = lane & 15, lg = lane >> 4;
    // staging coords: each wave-instr covers 8 rows x 64 cols (1KB).
    // lane l -> LDS row l>>3, chunk l&7; global source chunk pre-swizzled.
    const int srow = lane >> 3;                       // 0..7 within group
    const int scol = ((lane & 7) ^ srow) * 8;         // element col (XOR swz)
    const int sw = (lr & 7) << 4;                     // read-side swizzle

    f32x4 acc[4][4];
#pragma unroll
    for (int i = 0; i < 4; ++i)
#pragma unroll
        for (int j = 0; j < 4; ++j) acc[i][j] = 0.0f;

    for (int k0 = 0; k0 < K; k0 += 64) {
#pragma unroll
        for (int i = 0; i < 4; ++i) {
            int rg = w * 32 + i * 8;                  // group base row
            __builtin_amdgcn_global_load_lds(
                (gas_t)(A + (size_t)(m0 + rg + srow) * K + k0 + scol),
                (las_t)(As + rg * 64), 16, 0, 0);
            __builtin_amdgcn_global_load_lds(
                (gas_t)(Bt + (size_t)(n0 + rg + srow) * K + k0 + scol),
                (las_t)(Bs + rg * 64), 16, 0, 0);
        }
        __syncthreads();
#pragma unroll
        for (int kk = 0; kk < 2; ++kk) {
            const int cb = kk * 64 + lg * 8;
            bf16x8 af[4], bfr[4];
#pragma unroll
            for (int mi = 0; mi < 4; ++mi)
                af[mi] = ld_frag_s(&As[(wm + mi * 16 + lr) * 64], cb, sw);
#pragma unroll
            for (int ni = 0; ni < 4; ++ni)
                bfr[ni] = ld_frag_s(&Bs[(wn + ni * 16 + lr) * 64], cb, sw);
#pragma unroll
            for (int mi = 0; mi < 4; ++mi)
#pragma unroll
                for (int ni = 0; ni < 4; ++ni)
                    acc[mi][ni] = mfma_bf16(af[mi], bfr[ni], acc[mi][ni]);
        }
        __syncthreads();
    }
    // epilogue; C/D layout: col = lane&15, row = (lane>>4)*4 + reg
#pragma unroll
    for (int mi = 0; mi < 4; ++mi) {
#pragma unroll
        for (int ni = 0; ni < 4; ++ni) {
            int col = n0 + wn + ni * 16 + lr;
            float bval = BIAS ? bias[col] : 0.f;
#pragma unroll
            for (int r = 0; r < 4; ++r) {
                int row = m0 + wm + mi * 16 + lg * 4 + r;
                float v = acc[mi][ni][r];
                if (SANITIZE) v = __builtin_isfinite(v) ? v : 0.f;
                v += bval;
                if (OUT_BF16)
                    ((bf16*)Cv)[(size_t)row * N + col] = (bf16)v;
                else
                    ((float*)Cv)[(size_t)row * N + col] = v;
            }
        }
    }
}

// ---------------- postprocess: rmsnorm + rope, v transpose ----------------
// grid (32 lblocks, 16 heads, 2 batch) x 256 threads
__global__ __launch_bounds__(256) void k_post(const bf16* __restrict__ qkvb,
                                              const float* __restrict__ pe,
                                              const float* __restrict__ q_scale,
                                              const float* __restrict__ k_scale,
                                              bf16* __restrict__ qb,
                                              bf16* __restrict__ kb,
                                              bf16* __restrict__ vt) {
    const int lb = blockIdx.x, h = blockIdx.y, b = blockIdx.z;
    const int t = threadIdx.x;
    const int row = t >> 2, sub = t & 3;  // 64 rows x 4 lanes each
    const int l = lb * 64 + row;
    const int d0 = sub * 16;
    const size_t rowbase = ((size_t)(b * SEQ + l)) * (3 * DIMC) + h * HD;
    const size_t bh = (size_t)(b * HEADS + h);

#pragma unroll
    for (int qk = 0; qk < 2; ++qk) {
        const bf16* src = qkvb + rowbase + qk * DIMC + d0;
        const float* sc = qk ? k_scale : q_scale;
        bf16x8 v0 = *(const bf16x8*)src;
        bf16x8 v1 = *(const bf16x8*)(src + 8);
        float vals[16];
        float ss = 0.f;
#pragma unroll
        for (int j = 0; j < 8; ++j) {
            vals[j] = (float)v0[j];
            vals[8 + j] = (float)v1[j];
        }
#pragma unroll
        for (int j = 0; j < 16; ++j) ss += vals[j] * vals[j];
        ss += __shfl_xor(ss, 1, 64);
        ss += __shfl_xor(ss, 2, 64);
        float rms = rsqrtf(ss * (1.f / 64.f) + 1e-6f);
        // fold attention scale D^-0.5 and log2(e) into q
        const float outscale = qk ? 1.0f : 0.125f * 1.44269504088896340736f;
        bf16 ob[16];
#pragma unroll
        for (int j = 0; j < 16; j += 2) {
            int d = d0 + j;
            float e0 = vals[j] * rms * sc[d];
            float e1 = vals[j + 1] * rms * sc[d + 1];
            float4 pv = *(const float4*)(pe + (size_t)l * 128 + (d >> 1) * 4);
            float o0 = pv.x * e0 + pv.y * e1;
            float o1 = pv.z * e0 + pv.w * e1;
            ob[j] = (bf16)(o0 * outscale);
            ob[j + 1] = (bf16)(o1 * outscale);
        }
        bf16* dst = (qk ? kb : qb) + (bh * SEQ + l) * HD + d0;
        *(bf16x8*)dst = *(bf16x8*)&ob[0];
        *(bf16x8*)(dst + 8) = *(bf16x8*)&ob[8];
    }

    // V: cast + transpose to [B,H,D,L] via LDS
    __shared__ bf16 vlds[64][68];
    {
        const bf16* src = qkvb + rowbase + 2 * DIMC + d0;
        bf16x8 v0 = *(const bf16x8*)src;
        bf16x8 v1 = *(const bf16x8*)(src + 8);
        st8(&vlds[row][d0], v0);
        st8(&vlds[row][d0 + 8], v1);
    }
    __syncthreads();
    {
        const int d = t >> 2, c0 = (t & 3) * 16;
        bf16 ob[16];
#pragma unroll
        for (int j = 0; j < 16; ++j) ob[j] = vlds[c0 + j][d];
        bf16* dst = vt + (bh * HD + d) * SEQ + lb * 64 + c0;
        *(bf16x8*)dst = *(bf16x8*)&ob[0];
        *(bf16x8*)(dst + 8) = *(bf16x8*)&ob[8];
    }
}

// ---------------- flash attention (swapped QK^T, register P, O^T PV) ------
// grid (L/128 q-tiles, B*H), 512 threads = 8 waves, wave w -> q rows w*16..+16
// S^T = mfma(K, Q): lane holds S[q = w*16+(lane&15)][key = nk*16+(lane>>4)*4+r]
// -> softmax row is in-lane (16 vals) + 2 shfls; P == A-frag layout for PV,
//    PV computed as O^T = mfma(V^T, P^T) so O columns match lane's m/l.
// l computed via mfma(ones, P) (row-sum lands in the same lane as the q row);
// defer-max (THR=8 in exp2 domain) skips the rescale pass on most tiles.
// K/V double-buffered; next tile's global loads issued before compute (T14).
__global__ __launch_bounds__(512) void k_attn(const bf16* __restrict__ Q,
                                              const bf16* __restrict__ Kb,
                                              const bf16* __restrict__ Vt,
                                              bf16* __restrict__ O) {
    __shared__ bf16 Ks[2][64][68];
    __shared__ bf16 Vs[2][64][68];  // Vt tile: [d][key]
    const int qt = blockIdx.x, bh = blockIdx.y;
    const int b = bh >> 4, h = bh & 15;
    const int t = threadIdx.x, w = t >> 6, lane = t & 63;
    const int lr = lane & 15, lg = lane >> 4;
    const size_t baseQK = (size_t)bh * SEQ * HD;
    const size_t baseVt = (size_t)bh * HD * SEQ;

    // Q fragments straight from global (lane-private; 4 x 8B loads)
    const bf16* qp = Q + baseQK + (size_t)(qt * 128 + w * 16 + lr) * HD;
    bf16x8 qf0 = ld_frag(qp + lg * 4);
    bf16x8 qf1 = ld_frag(qp + 32 + lg * 4);

    const int sr = t >> 3, scol = (t & 7) * 8;  // staging coords (512 chunks)
    // stage K/V tile 0
    {
        bf16x8 kv = *(const bf16x8*)(Kb + baseQK + (size_t)sr * HD + scol);
        bf16x8 vv = *(const bf16x8*)(Vt + baseVt + (size_t)sr * SEQ + scol);
        st8(&Ks[0][sr][scol], kv);
        st8(&Vs[0][sr][scol], vv);
    }
    __syncthreads();

    bf16x8 ones;
#pragma unroll
    for (int j = 0; j < 8; ++j) ones[j] = (bf16)1.0f;

    f32x4 oacc[4];
#pragma unroll
    for (int i = 0; i < 4; ++i) oacc[i] = 0.0f;
    f32x4 lacc = 0.0f;
    float m_s = -1e30f;

    int cur = 0;
    for (int kt = 0; kt < SEQ / 64; ++kt) {
        // issue next tile's global loads early (latency hidden under compute)
        bf16x8 kreg, vreg;
        const bool pf = (kt + 1) < SEQ / 64;
        if (pf) {
            kreg = *(const bf16x8*)(Kb + baseQK + (size_t)((kt + 1) * 64 + sr) * HD + scol);
            vreg = *(const bf16x8*)(Vt + baseVt + (size_t)sr * SEQ + (kt + 1) * 64 + scol);
        }
        // QK^T on current tile
        __builtin_amdgcn_s_setprio(1);
        f32x4 s[4];
#pragma unroll
        for (int nk = 0; nk < 4; ++nk) {
            f32x4 a = 0.0f;
            a = mfma_bf16(ld_frag(&Ks[cur][nk * 16 + lr][lg * 4]), qf0, a);
            a = mfma_bf16(ld_frag(&Ks[cur][nk * 16 + lr][32 + lg * 4]), qf1, a);
            s[nk] = a;
        }
        __builtin_amdgcn_s_setprio(0);
        // row max: 16 in-lane + 2 shfls (q pre-scaled into exp2 domain)
        float tm = fmaxf(fmaxf(s[0][0], s[0][1]), fmaxf(s[0][2], s[0][3]));
#pragma unroll
        for (int nk = 1; nk < 4; ++nk)
            tm = fmaxf(tm, fmaxf(fmaxf(s[nk][0], s[nk][1]),
                                 fmaxf(s[nk][2], s[nk][3])));
        tm = fmaxf(tm, __shfl_xor(tm, 16, 64));
        tm = fmaxf(tm, __shfl_xor(tm, 32, 64));
        // defer-max: only rescale when some row grew past THR=8
        if (!__all(tm <= m_s + 8.f)) {
            float mnew = fmaxf(m_s, tm);
            float alpha = exp2f(m_s - mnew);
            m_s = mnew;
#pragma unroll
            for (int nd = 0; nd < 4; ++nd)
#pragma unroll
                for (int r2 = 0; r2 < 4; ++r2) oacc[nd][r2] *= alpha;
#pragma unroll
            for (int r2 = 0; r2 < 4; ++r2) lacc[r2] *= alpha;
        }
        // P (bounded by 2^8) packed straight into A-frag layout
        bf16x8 pa0, pa1;
#pragma unroll
        for (int j = 0; j < 4; ++j) {
            pa0[j]     = (bf16)exp2f(s[0][j] - m_s);
            pa0[4 + j] = (bf16)exp2f(s[1][j] - m_s);
            pa1[j]     = (bf16)exp2f(s[2][j] - m_s);
            pa1[4 + j] = (bf16)exp2f(s[3][j] - m_s);
        }
        __builtin_amdgcn_s_setprio(1);
        // l row-sum via ones-MFMA (lands in col q = lane&15, all regs equal)
        lacc = mfma_bf16(ones, pa0, lacc);
        lacc = mfma_bf16(ones, pa1, lacc);
#pragma unroll
        for (int nd = 0; nd < 4; ++nd) {
            oacc[nd] = mfma_bf16(ld_frag(&Vs[cur][nd * 16 + lr][lg * 4]), pa0, oacc[nd]);
            oacc[nd] = mfma_bf16(ld_frag(&Vs[cur][nd * 16 + lr][32 + lg * 4]), pa1, oacc[nd]);
        }
        __builtin_amdgcn_s_setprio(0);
        // write prefetched tile into the other buffer (readers synced at kt-1's barrier)
        if (pf) {
            st8(&Ks[cur ^ 1][sr][scol], kreg);
            st8(&Vs[cur ^ 1][sr][scol], vreg);
        }
        __syncthreads();
        cur ^= 1;
    }
    // epilogue: O^T[d][q] regs -> O[b, q, h*64+d], d = nd*16+lg*4+r (4 consecutive)
    {
        float inv = 1.f / lacc[0];
        int q = qt * 128 + w * 16 + lr;
#pragma unroll
        for (int nd = 0; nd < 4; ++nd) {
            bf16x4 ov;
#pragma unroll
            for (int r2 = 0; r2 < 4; ++r2) {
                float v = oacc[nd][r2] * inv;
                v = fminf(fmaxf(v, -10000.f), 10000.f);
                ov[r2] = (bf16)v;
            }
            *(bf16x4*)(O + ((size_t)(b * SEQ + q)) * DIMC + h * HD + nd * 16 + lg * 4) = ov;
        }
    }
}

extern "C" void kernel_launch(void* const* d_in, const int* in_sizes, int n_in,
                              void* d_out, int out_size, void* d_ws, size_t ws_size,
                              hipStream_t stream) {
    const float* x = (const float*)d_in[0];
    const float* pe = (const float*)d_in[1];
    const float* qkv_w = (const float*)d_in[2];
    const float* q_scale = (const float*)d_in[3];
    const float* k_scale = (const float*)d_in[4];
    const float* proj_w = (const float*)d_in[5];
    const float* proj_b = (const float*)d_in[6];
    float* out = (float*)d_out;
    char* ws = (char*)d_ws;

    // workspace layout (64 MB total)
    bf16* xb = (bf16*)(ws);                              // 8 MB  [4096][1024]
    bf16* wqkv = (bf16*)(ws + (8u << 20));               // 6 MB  [3072][1024]
    bf16* wproj = (bf16*)(ws + (14u << 20));             // 2 MB  [1024][1024]
    bf16* qkvb = (bf16*)(ws + (16u << 20));              // 24 MB [4096][3072]
    bf16* ao = (bf16*)(ws + (16u << 20));                // 8 MB, overlays qkvb (dead)
    bf16* qb = (bf16*)(ws + (40u << 20));                // 8 MB  [B,H,L,D]
    bf16* kb = (bf16*)(ws + (48u << 20));                // 8 MB  [B,H,L,D]
    bf16* vt = (bf16*)(ws + (56u << 20));                // 8 MB  [B,H,D,L]

    k_prep_x<<<4096, 256, 0, stream>>>(x, xb);
    k_cast<<<3072, 256, 0, stream>>>(qkv_w, wqkv);
    k_cast<<<1024, 256, 0, stream>>>(proj_w, wproj);
    // qkv = x_c @ qkv_w^T, nan_to_num, -> bf16
    k_gemm_bt<true, false, true>
        <<<dim3(24, 32), 256, 0, stream>>>(xb, wqkv, (void*)qkvb, nullptr, 3072, 1024);
    k_post<<<dim3(32, HEADS, BATCH), 256, 0, stream>>>(qkvb, pe, q_scale, k_scale, qb, kb, vt);
    k_attn<<<dim3(SEQ / 128, BATCH * HEADS), 512, 0, stream>>>(qb, kb, vt, ao);
    // out = clip(attn_out) @ proj_w^T + proj_b (clip already applied in k_attn)
    k_gemm_bt<false, true, false>
        <<<dim3(8, 32), 256, 0, stream>>>(ao, wproj, (void*)out, proj_b, 1024, 1024);
}